// Round 6
// baseline (19338.904 us; speedup 1.0000x reference)
//
#include <hip/hip_runtime.h>

// ============================================================================
// 2-layer tanh RNN (B=128,S=512,IN=128,H=512) + linear head (C=1000) + logsoftmax
//
// Round-16: STRUCTURAL — split H across WG pairs (de-duplicate MFMA work).
//   Through R15: per-CU MFMA work was invariant (16-row tile per WG forced by
//   MFMA M=16; B=128 = 8 groups) -> per-SIMD floor 1306 cy/step; measured
//   2912 cy with micro-scheduling exhausted (R14 -14%, R15 null).
//   Fix: 128 WGs; pair (bid, bid^64) shares batch group pg=bid&63 (partner is
//   same-XCD under %8 round-robin; correctness doesn't rely on it). Each WG
//   computes ONE HALF of H (16 jtg; wave owns 2 jtg, wa = 64 AGPRs): MFMA and
//   EPI per wave halve. Per step, pair exchanges its h-half (i8, 4KB/WG) via
//   parity-double-buffered global buffer + per-wave monotone flags
//   (__hip_atomic release/acquire, AGENT scope). Own-kt MFMAs run while the
//   partner's flag/data arrive; i32 accumulation is associative -> numerics
//   BIT-IDENTICAL to R15. Two lgkm-only barriers/step (B2 after remote
//   ds_write, B1 after EPI). Flags zeroed each launch by packi8 (stream
//   order); 128 WGs <= 256 CUs so all co-resident (no spin deadlock).
//
// ws layout: bufA = ws (64 MB): xp0/hs0 in place; Wq1 head + hlast @ +1MB,
//            xbuf1/flags1 @ +32MB (dead hs0) for rec1.
//            bufB = ws+64MB: Wq0/sc0 head (dead after rec0), xbuf0/flags0
//            @ +32MB for rec0; later xp1 overwrites all of bufB.
// ============================================================================

using short8  = __attribute__((ext_vector_type(8))) short;
using floatx4 = __attribute__((ext_vector_type(4))) float;
using i32x4   = __attribute__((ext_vector_type(4))) int;
using f32x4   = __attribute__((ext_vector_type(4))) float;

#define DEV static __device__ __forceinline__
#define PINA(x) asm volatile("" : "+a"(x))
#define PINV(x) asm volatile("" : "+v"(x))

#define TWO_LOG2E 2.8853900817779268f

#define SGB(m, n) __builtin_amdgcn_sched_group_barrier((m), (n), 0)

DEV void lds_barrier() {
    // LDS-only barrier: do NOT drain vmcnt (global stores/loads keep flying).
    asm volatile("s_waitcnt lgkmcnt(0)\n\ts_barrier" ::: "memory");
}

DEV unsigned short f2bf(float f) {
    union { float f; unsigned u; } v; v.f = f;
    unsigned r = (v.u + 0x7fffu + ((v.u >> 16) & 1u)) >> 16;
    return (unsigned short)r;
}

DEV unsigned short f2h(float f) {
    union { _Float16 h; unsigned short u; } c; c.h = (_Float16)f;
    return c.u;
}

// ---------------------------------------------------------------------------
// packi8: one block (64 thr) per W row j. Row absmax -> per-row scale;
// quantize to i8 in A-frag layout for mfma_i32_16x16x64_i8.
// sc2[j] = mx_j / 127^2 * 2*log2(e). Block 0 also zeroes the 1024 u32
// exchange flags for the following rec launch (stream-ordered).
// ---------------------------------------------------------------------------
__global__ __launch_bounds__(64) void packi8_kernel(
    const float* __restrict__ W, signed char* __restrict__ Wq,
    float* __restrict__ sc2, unsigned* __restrict__ flags)
{
    const int j = blockIdx.x;            // 0..511
    const int t = threadIdx.x;           // 0..63

    if (j == 0) {
        #pragma unroll
        for (int i = 0; i < 16; ++i) flags[t * 16 + i] = 0u;
    }

    const float* row = W + (size_t)j * 512;

    float4 a = *(const float4*)(row + t * 8);
    float4 b = *(const float4*)(row + t * 8 + 4);
    float m = fmaxf(fmaxf(fabsf(a.x), fabsf(a.y)), fmaxf(fabsf(a.z), fabsf(a.w)));
    m = fmaxf(m, fmaxf(fmaxf(fabsf(b.x), fabsf(b.y)), fmaxf(fabsf(b.z), fabsf(b.w))));
    #pragma unroll
    for (int off = 32; off; off >>= 1) m = fmaxf(m, __shfl_down(m, off, 64));
    m = __shfl(m, 0, 64);
    if (t == 0) sc2[j] = m * (1.0f / (127.f * 127.f)) * TWO_LOG2E;

    if (t < 32) {
        const int kt = t >> 2, lq = t & 3;
        const int jtg = j >> 4, lm = j & 15;
        const float r = 127.f / m;
        int w4[4];
        #pragma unroll
        for (int w = 0; w < 4; ++w) {
            int v = 0;
            #pragma unroll
            for (int e = 0; e < 4; ++e) {
                int q = __float2int_rn(row[kt * 64 + lq * 16 + w * 4 + e] * r);
                v |= (q & 255) << (8 * e);
            }
            w4[w] = v;
        }
        i32x4 pk; pk[0] = w4[0]; pk[1] = w4[1]; pk[2] = w4[2]; pk[3] = w4[3];
        *(i32x4*)(Wq + ((size_t)((jtg * 8 + kt) * 64 + lq * 16 + lm)) * 16) = pk;
    }
}

// ---------------------------------------------------------------------------
// proj: out[m=t*128+b][n] = f16( (A[m][:]·W[n][:] + b1[n]+b2[n]) * oscale )
// oscale = 2*log2(e): rec consumes xp only inside exp2 arguments (via
// v_fma_mix_f32, so xp lives as packed f16).
// ---------------------------------------------------------------------------
template <int K, int MODE>
__global__ __launch_bounds__(256, 2) void proj_kernel(
    const void* __restrict__ Aptr, const float* __restrict__ W,
    const float* __restrict__ b1, const float* __restrict__ b2,
    unsigned short* __restrict__ out, float oscale)
{
    constexpr int LDA = 40;
    __shared__ unsigned short As[128 * LDA];
    __shared__ unsigned short Ws[64 * LDA];

    const int tid  = threadIdx.x;
    const int lane = tid & 63, wave = tid >> 6;
    const int lm   = lane & 15, lq = lane >> 4;
    const int nbase = blockIdx.x * 64;
    const int mtile = blockIdx.y;
    const int mbase = mtile * 128;

    floatx4 acc[2][4] = {};

    const int ar = tid >> 1, ak = (tid & 1) * 16;
    const int wr = tid >> 2, wk = (tid & 3) * 8;

    for (int k0 = 0; k0 < K; k0 += 32) {
        if (MODE == 0) {
            const float* x   = (const float*)Aptr;
            const float* src = x + ((size_t)ar * 512 + mtile) * 128 + (k0 + ak);
            float4 f0 = *(const float4*)(src + 0);
            float4 f1 = *(const float4*)(src + 4);
            float4 f2 = *(const float4*)(src + 8);
            float4 f3 = *(const float4*)(src + 12);
            unsigned short* d = As + ar * LDA + ak;
            d[0]=f2bf(f0.x); d[1]=f2bf(f0.y); d[2]=f2bf(f0.z); d[3]=f2bf(f0.w);
            d[4]=f2bf(f1.x); d[5]=f2bf(f1.y); d[6]=f2bf(f1.z); d[7]=f2bf(f1.w);
            d[8]=f2bf(f2.x); d[9]=f2bf(f2.y); d[10]=f2bf(f2.z); d[11]=f2bf(f2.w);
            d[12]=f2bf(f3.x); d[13]=f2bf(f3.y); d[14]=f2bf(f3.z); d[15]=f2bf(f3.w);
        } else {
            const unsigned short* h =
                (const unsigned short*)Aptr + (size_t)(mbase + ar) * K + k0 + ak;
            short8 v0 = *(const short8*)(h);
            short8 v1 = *(const short8*)(h + 8);
            *(short8*)(As + ar * LDA + ak)     = v0;
            *(short8*)(As + ar * LDA + ak + 8) = v1;
        }
        {
            const float* src = W + (size_t)(nbase + wr) * K + k0 + wk;
            float4 f0 = *(const float4*)(src);
            float4 f1 = *(const float4*)(src + 4);
            unsigned short* d = Ws + wr * LDA + wk;
            d[0]=f2bf(f0.x); d[1]=f2bf(f0.y); d[2]=f2bf(f0.z); d[3]=f2bf(f0.w);
            d[4]=f2bf(f1.x); d[5]=f2bf(f1.y); d[6]=f2bf(f1.z); d[7]=f2bf(f1.w);
        }
        __syncthreads();

        short8 af0 = *(const short8*)(As + (wave * 32 +  0 + lm) * LDA + lq * 8);
        short8 af1 = *(const short8*)(As + (wave * 32 + 16 + lm) * LDA + lq * 8);
        #pragma unroll
        for (int nt = 0; nt < 4; ++nt) {
            short8 bf = *(const short8*)(Ws + (nt * 16 + lm) * LDA + lq * 8);
            acc[0][nt] = __builtin_amdgcn_mfma_f32_16x16x32_bf16(af0, bf, acc[0][nt], 0, 0, 0);
            acc[1][nt] = __builtin_amdgcn_mfma_f32_16x16x32_bf16(af1, bf, acc[1][nt], 0, 0, 0);
        }
        __syncthreads();
    }

    #pragma unroll
    for (int nt = 0; nt < 4; ++nt) {
        const int n = nbase + nt * 16 + lm;
        const float bias = b1[n] + b2[n];
        #pragma unroll
        for (int mt = 0; mt < 2; ++mt) {
            const int mrow = mbase + wave * 32 + mt * 16 + lq * 4;
            #pragma unroll
            for (int r = 0; r < 4; ++r)
                out[(size_t)(mrow + r) * 512 + n] = f2h((acc[mt][nt][r] + bias) * oscale);
        }
    }
}

// ---------------------------------------------------------------------------
// rec16: 128 WGs x 512 thr (8 waves, 2/SIMD). Pair (bid, bid^64) shares
// batch group pg = bid&63 (bb = pg*2 + (lm&1), replicas lm>=2, stores lm<2).
// half = bid>>6 selects the H-half: wave owns 2 jtg (jtg = half*16+wave*2+j).
// W_hh(i8) slice = 64 AGPRs/wave. h state: i8 LDS [2][16 b][512 j], granule
// swizzle g' = g ^ lm; OWN half written by EPI, REMOTE half ds_written from
// the partner's exchange buffer each step. Exchange: parity-dbuf global
// (8B/lane atomic, AGENT) + per-wave monotone flag (release/acquire).
// Step: xv prefetch | own-kt ds_reads+8 MFMA | poll+load+ds_write remote |
// B2 | remote-kt ds_reads+8 MFMA (EPI0 interleaved) | EPI1 | xstore+flag |
// hst | B1. i32 accumulate own-kt-first: bit-identical.
// MODE 0: store h_t bf16 to hs_out (in-place over xp). MODE 1: t=511 -> h_last.
// ---------------------------------------------------------------------------

#define RD8(P, KT)                                                             \
  (*(const i32x4*)(&h2[P][0] + lm * 512 + ((((KT) * 4 + lq)) ^ lm) * 16))

#define MF(J, KT, CIN)                                                         \
  acc[J] = __builtin_amdgcn_mfma_i32_16x16x64_i8(wa[J][KT], bfr[KT], CIN, 0, 0, 0)

// branchless epilogue for chain JJ (0/1): tanh -> QV (f32x4), QB (packed i8),
// ds_write own granule into h2[P^1].
#define EPI_MAIN16(JJ, P, QV, QB)                                              \
  {                                                                            \
    const int jtg = half * 16 + wave * 2 + (JJ);                               \
    float a0 = (float)acc[JJ][0], a1 = (float)acc[JJ][1];                      \
    float a2 = (float)acc[JJ][2], a3 = (float)acc[JJ][3];                      \
    float z0, z1, z2, z3;                                                      \
    asm("v_fma_mix_f32 %0, %1, %2, %3 op_sel:[0,0,0] op_sel_hi:[0,0,1]"        \
        : "=v"(z0) : "v"(a0), "v"(sc[JJ][0]), "v"(xv[P][JJ].x));               \
    asm("v_fma_mix_f32 %0, %1, %2, %3 op_sel:[0,0,1] op_sel_hi:[0,0,1]"        \
        : "=v"(z1) : "v"(a1), "v"(sc[JJ][1]), "v"(xv[P][JJ].x));               \
    asm("v_fma_mix_f32 %0, %1, %2, %3 op_sel:[0,0,0] op_sel_hi:[0,0,1]"        \
        : "=v"(z2) : "v"(a2), "v"(sc[JJ][2]), "v"(xv[P][JJ].y));               \
    asm("v_fma_mix_f32 %0, %1, %2, %3 op_sel:[0,0,1] op_sel_hi:[0,0,1]"        \
        : "=v"(z3) : "v"(a3), "v"(sc[JJ][3]), "v"(xv[P][JJ].y));               \
    float e0 = __builtin_amdgcn_exp2f(z0);                                     \
    float e1 = __builtin_amdgcn_exp2f(z1);                                     \
    float e2 = __builtin_amdgcn_exp2f(z2);                                     \
    float e3 = __builtin_amdgcn_exp2f(z3);                                     \
    float q0 = fmaf(-2.f, __builtin_amdgcn_rcpf(e0 + 1.f), 1.f);               \
    float q1 = fmaf(-2.f, __builtin_amdgcn_rcpf(e1 + 1.f), 1.f);               \
    float q2 = fmaf(-2.f, __builtin_amdgcn_rcpf(e2 + 1.f), 1.f);               \
    float q3 = fmaf(-2.f, __builtin_amdgcn_rcpf(e3 + 1.f), 1.f);               \
    QV.x = q0; QV.y = q1; QV.z = q2; QV.w = q3;                                \
    unsigned m0 = __float_as_uint(fmaf(q0, 127.f, 12582912.f));                \
    unsigned m1 = __float_as_uint(fmaf(q1, 127.f, 12582912.f));                \
    unsigned m2 = __float_as_uint(fmaf(q2, 127.f, 12582912.f));                \
    unsigned m3 = __float_as_uint(fmaf(q3, 127.f, 12582912.f));                \
    unsigned lo = __builtin_amdgcn_perm(m1, m0, 0x00000400u);                  \
    unsigned hi = __builtin_amdgcn_perm(m3, m2, 0x00000400u);                  \
    QB = __builtin_amdgcn_perm(hi, lo, 0x05040100u);                           \
    *(unsigned*)(&h2[(P) ^ 1][0] + lm * 512 + ((jtg ^ lm) << 4) + lq * 4) = QB; \
  }

// divergent global-store part
#define EPI_ST16(JJ, QV, TCUR)                                                 \
  {                                                                            \
    if (MODE == 0) {                                                           \
      if (lm < 2) {                                                            \
        uint2 st;                                                              \
        st.x = __builtin_amdgcn_perm(__float_as_uint(QV.y), __float_as_uint(QV.x), 0x07060302u); \
        st.y = __builtin_amdgcn_perm(__float_as_uint(QV.w), __float_as_uint(QV.z), 0x07060302u); \
        *(uint2*)(hst + (JJ) * 16) = st;                                       \
      }                                                                        \
    } else if ((TCUR) == 511) {                                                \
      if (lm < 2) {                                                            \
        const int jtg = half * 16 + wave * 2 + (JJ);                           \
        *(float4*)(h_last + (size_t)bb * 512 + jtg * 16 + lq * 4) = QV;        \
      }                                                                        \
    }                                                                          \
  }

#define REC_STEP16(P, TCUR)                                                    \
  {                                                                            \
    i32x4 bfr[8];                                                              \
    float4 qv0, qv1;                                                           \
    unsigned qb0, qb1;                                                         \
    /* next-step xv prefetch (2 loads) */                                      \
    xv[(P) ^ 1][0] = *(const uint2*)(xpt);                                     \
    xv[(P) ^ 1][1] = *(const uint2*)(xpt + 16);                                \
    xpt += ((TCUR) < 510) ? 65536 : 0;                                         \
    /* region A: own-half ds_reads + 8 MFMAs (j0/j1 interleaved) */            \
    bfr[okt + 0] = RD8(P, okt + 0);                                            \
    bfr[okt + 1] = RD8(P, okt + 1);                                            \
    bfr[okt + 2] = RD8(P, okt + 2);                                            \
    bfr[okt + 3] = RD8(P, okt + 3);                                            \
    MF(0, okt + 0, z4);      MF(1, okt + 0, z4);                               \
    MF(0, okt + 1, acc[0]);  MF(1, okt + 1, acc[1]);                           \
    MF(0, okt + 2, acc[0]);  MF(1, okt + 2, acc[1]);                           \
    MF(0, okt + 3, acc[0]);  MF(1, okt + 3, acc[1]);                           \
    SGB(0x20, 2);   /* xv loads first */                                       \
    SGB(0x100, 2);  /* 2 ds_reads ahead */                                     \
    SGB(0x8, 1); SGB(0x100, 1);                                                \
    SGB(0x8, 1); SGB(0x100, 1);                                                \
    SGB(0x8, 6);                                                               \
    /* exchange-in: partner's h_t half (skip t=0: h_0 = 0, LDS pre-zeroed) */  \
    if ((TCUR) != 0) {                                                         \
      while (__hip_atomic_load(fl_rd, __ATOMIC_ACQUIRE,                        \
                               __HIP_MEMORY_SCOPE_AGENT) < (unsigned)(TCUR)) {} \
      unsigned long long d = __hip_atomic_load(xb_rd + (P) * 512,              \
          __ATOMIC_RELAXED, __HIP_MEMORY_SCOPE_AGENT);                         \
      unsigned char* hb = &h2[P][0] + lm * 512 + lq * 4;                       \
      const int gr0 = (((half ^ 1) * 16 + wave * 2) ^ lm);                     \
      *(unsigned*)(hb + (gr0 << 4))       = (unsigned)d;                       \
      *(unsigned*)(hb + ((gr0 ^ 1) << 4)) = (unsigned)(d >> 32);               \
    }                                                                          \
    lds_barrier(); /* B2: remote half of h_t in LDS */                         \
    /* region B: remote-kt ds_reads + 8 MFMAs; EPI0 interleaved */             \
    bfr[rkt + 0] = RD8(P, rkt + 0);                                            \
    bfr[rkt + 1] = RD8(P, rkt + 1);                                            \
    bfr[rkt + 2] = RD8(P, rkt + 2);                                            \
    bfr[rkt + 3] = RD8(P, rkt + 3);                                            \
    MF(0, rkt + 0, acc[0]);  MF(1, rkt + 0, acc[1]);                           \
    MF(0, rkt + 1, acc[0]);  MF(1, rkt + 1, acc[1]);                           \
    MF(0, rkt + 2, acc[0]);  MF(1, rkt + 2, acc[1]);                           \
    MF(0, rkt + 3, acc[0]);  MF(1, rkt + 3, acc[1]);                           \
    EPI_MAIN16(0, P, qv0, qb0);                                                \
    SGB(0x100, 2);                                                             \
    SGB(0x8, 1); SGB(0x100, 1);                                                \
    SGB(0x8, 1); SGB(0x100, 1);                                                \
    SGB(0x8, 2);                                                               \
    SGB(0x8, 1); SGB(0x2, 4);                                                  \
    SGB(0x8, 1); SGB(0x2, 4);                                                  \
    SGB(0x8, 1); SGB(0x2, 4);                                                  \
    SGB(0x8, 1); SGB(0x2, 4);                                                  \
    EPI_MAIN16(1, P, qv1, qb1);                                                \
    /* exchange-out: own h_{t+1} half -> parity P^1, then per-wave flag */     \
    __hip_atomic_store(xb_wr + ((P) ^ 1) * 512,                                \
        (unsigned long long)qb0 | ((unsigned long long)qb1 << 32),             \
        __ATOMIC_RELAXED, __HIP_MEMORY_SCOPE_AGENT);                           \
    if (lane == 0)                                                             \
      __hip_atomic_store(fl_wr, (unsigned)((TCUR) + 1),                        \
          __ATOMIC_RELEASE, __HIP_MEMORY_SCOPE_AGENT);                         \
    EPI_ST16(0, qv0, TCUR);                                                    \
    EPI_ST16(1, qv1, TCUR);                                                    \
    if (MODE == 0) hst += 65536;                                               \
    lds_barrier(); /* B1: own half of h_{t+1} in LDS */                        \
  }

template <int MODE>
__global__ __launch_bounds__(512, 2) void rec16_kernel(
    const signed char* __restrict__ Wq,   // [32 jtg][8 kt][64 lane][16] i8
    const float* __restrict__ sc2,        // [512] row scale * 2log2e / 127^2
    const unsigned short* xp,             // [S][B][H] f16 SCALED (aliases hs_out)
    unsigned short* hs_out,               // [S][B][H] bf16
    float* __restrict__ h_last,           // [B][H] fp32
    unsigned long long* __restrict__ xbuf, // [64 pg][2 half][2 par][8 w][64 ln] u64
    unsigned* __restrict__ flags)          // [64 pg][2 half][8 w]
{
    __shared__ unsigned char h2[2][16 * 512];   // 16 KB

    const int tid  = threadIdx.x;
    const int lane = tid & 63;
    const int wave = tid >> 6;              // 0..7
    const int lm   = lane & 15, lq = lane >> 4;
    const int bid  = blockIdx.x;            // 0..127
    const int half = bid >> 6;              // 0: j in [0,256), 1: [256,512)
    const int pg   = bid & 63;              // batch group (partner = bid^64)
    const int bb   = pg * 2 + (lm & 1);     // 2 real batches over 16 rows
    const int okt  = half * 4;              // own kt base (k-range of own half)
    const int rkt  = 4 - half * 4;          // remote kt base

    // ---- W slice in AGPRs: 2 jtg x 8 kt x int4 = 64 AGPRs per wave ----
    i32x4 wa[2][8];
    #pragma unroll
    for (int j = 0; j < 2; ++j) {
        const int jtg = half * 16 + wave * 2 + j;
        #pragma unroll
        for (int kt = 0; kt < 8; ++kt)
            wa[j][kt] = *(const i32x4*)(Wq + ((size_t)((jtg * 8 + kt) * 64 + lane)) * 16);
    }
    #pragma unroll
    for (int j = 0; j < 2; ++j)
        #pragma unroll
        for (int kt = 0; kt < 8; ++kt)
            PINA(wa[j][kt]);

    // ---- per-lane fused dequant scales, pinned ----
    f32x4 sc[2];
    #pragma unroll
    for (int j = 0; j < 2; ++j)
        sc[j] = *(const f32x4*)(sc2 + (half * 16 + wave * 2 + j) * 16 + lq * 4);
    #pragma unroll
    for (int j = 0; j < 2; ++j) PINV(sc[j]);

    // ---- zero h buffers (h_0 = 0, both halves) ----
    for (int i = tid; i < 4096; i += 512) ((int*)h2)[i] = 0;
    __syncthreads();

    // per-thread streaming pointers (row stride 128*512 elems per step)
    const unsigned short* xpt = xp + (size_t)bb * 512 + half * 256 + wave * 32 + lq * 4;
    unsigned short*       hst = hs_out + (size_t)bb * 512 + half * 256 + wave * 32 + lq * 4;

    // exchange pointers (parity offset = 512 u64 added per step)
    unsigned long long* xb_wr =
        xbuf + ((((size_t)pg * 2 + half) * 2) * 8 + wave) * 64 + lane;
    const unsigned long long* xb_rd =
        xbuf + ((((size_t)pg * 2 + (half ^ 1)) * 2) * 8 + wave) * 64 + lane;
    unsigned* fl_wr       = flags + (pg * 2 + half) * 8 + wave;
    const unsigned* fl_rd = flags + (pg * 2 + (half ^ 1)) * 8 + wave;

    uint2 xv[2][2];
    i32x4 acc[2];
    const i32x4 z4 = {0, 0, 0, 0};

    // ---- prologue: xv[0] = row 0 ----
    xv[0][0] = *(const uint2*)(xpt);
    xv[0][1] = *(const uint2*)(xpt + 16);
    xpt += 65536;

    for (int t = 0; t < 512; t += 2) {
        REC_STEP16(0, t);
        REC_STEP16(1, t + 1);
    }
}

// ---------------------------------------------------------------------------
// head: logits[b][c] = h_last[b][:]·W_out[c][:] + b_out[c]; log_softmax rows.
// ---------------------------------------------------------------------------
__global__ __launch_bounds__(256, 2) void head_kernel(
    const float* __restrict__ hl, const float* __restrict__ Wout,
    const float* __restrict__ bout, float* __restrict__ out)
{
    __shared__ float hrow[512];
    __shared__ float lg[1000];
    __shared__ float red[8];
    const int b = blockIdx.x, tid = threadIdx.x;

    hrow[tid]       = hl[(size_t)b * 512 + tid];
    hrow[tid + 256] = hl[(size_t)b * 512 + 256 + tid];
    __syncthreads();

    float lmax = -1e30f;
    for (int c = tid; c < 1000; c += 256) {
        const float4* w4 = (const float4*)(Wout + (size_t)c * 512);
        float a0 = 0.f, a1 = 0.f, a2 = 0.f, a3 = 0.f;
        #pragma unroll 4
        for (int k = 0; k < 128; ++k) {
            float4 w = w4[k];
            a0 += hrow[4 * k + 0] * w.x;
            a1 += hrow[4 * k + 1] * w.y;
            a2 += hrow[4 * k + 2] * w.z;
            a3 += hrow[4 * k + 3] * w.w;
        }
        float acc = bout[c] + (a0 + a1) + (a2 + a3);
        lg[c] = acc;
        lmax = fmaxf(lmax, acc);
    }
    #pragma unroll
    for (int off = 32; off; off >>= 1) lmax = fmaxf(lmax, __shfl_down(lmax, off, 64));
    if ((tid & 63) == 0) red[tid >> 6] = lmax;
    __syncthreads();
    if (tid == 0) red[4] = fmaxf(fmaxf(red[0], red[1]), fmaxf(red[2], red[3]));
    __syncthreads();
    const float M = red[4];

    float lsum = 0.f;
    for (int c = tid; c < 1000; c += 256) lsum += __expf(lg[c] - M);
    #pragma unroll
    for (int off = 32; off; off >>= 1) lsum += __shfl_down(lsum, off, 64);
    __syncthreads();
    if ((tid & 63) == 0) red[tid >> 6] = lsum;
    __syncthreads();
    if (tid == 0) red[5] = M + __logf(red[0] + red[1] + red[2] + red[3]);
    __syncthreads();
    const float lse = red[5];

    for (int c = tid; c < 1000; c += 256)
        out[(size_t)b * 1000 + c] = lg[c] - lse;
}

// ---------------------------------------------------------------------------
extern "C" void kernel_launch(void* const* d_in, const int* in_sizes, int n_in,
                              void* d_out, int out_size, void* d_ws, size_t ws_size,
                              hipStream_t stream)
{
    const float* x    = (const float*)d_in[0];
    const float* Wih0 = (const float*)d_in[1];
    const float* Whh0 = (const float*)d_in[2];
    const float* bih0 = (const float*)d_in[3];
    const float* bhh0 = (const float*)d_in[4];
    const float* Wih1 = (const float*)d_in[5];
    const float* Whh1 = (const float*)d_in[6];
    const float* bih1 = (const float*)d_in[7];
    const float* bhh1 = (const float*)d_in[8];
    const float* Wout = (const float*)d_in[9];
    const float* bout = (const float*)d_in[10];
    float* out = (float*)d_out;

    char* ws = (char*)d_ws;
    unsigned short* bufA = (unsigned short*)ws;                              // 64 MB
    unsigned short* bufB = (unsigned short*)(ws + (size_t)64 * 1024 * 1024);
    signed char* Wq0 = (signed char*)bufB;                                   // 256 KB (dead after rec0)
    float*       sc0 = (float*)((char*)bufB + 262144);                       // 2 KB
    signed char* Wq1 = (signed char*)bufA;                                   // 256 KB (after proj1 consumed bufA)
    float*       sc1 = (float*)(ws + 262144);                                // 2 KB
    float*     hlast = (float*)(ws + (size_t)1 * 1024 * 1024);               // 256 KB

    // exchange buffers: 1 MB xbuf + 4 KB flags, in regions dead at rec time.
    unsigned long long* xbuf0 = (unsigned long long*)(ws + (size_t)96 * 1024 * 1024); // bufB+32MB (free during rec0)
    unsigned*          flags0 = (unsigned*)(ws + (size_t)97 * 1024 * 1024);
    unsigned long long* xbuf1 = (unsigned long long*)(ws + (size_t)32 * 1024 * 1024); // bufA+32MB (dead hs0, rec1)
    unsigned*          flags1 = (unsigned*)(ws + (size_t)33 * 1024 * 1024);

    const dim3 pgrid(8, 512);

    packi8_kernel<<<512, 64, 0, stream>>>(Whh0, Wq0, sc0, flags0);
    proj_kernel<128, 0><<<pgrid, 256, 0, stream>>>((const void*)x, Wih0, bih0, bhh0, bufA, TWO_LOG2E);
    rec16_kernel<0><<<128, 512, 0, stream>>>(Wq0, sc0, bufA, bufA, hlast, xbuf0, flags0);

    proj_kernel<512, 1><<<pgrid, 256, 0, stream>>>((const void*)bufA, Wih1, bih1, bhh1, bufB, TWO_LOG2E);
    packi8_kernel<<<512, 64, 0, stream>>>(Whh1, Wq1, sc1, flags1);
    rec16_kernel<1><<<128, 512, 0, stream>>>(Wq1, sc1, bufB, bufB, hlast, xbuf1, flags1);

    head_kernel<<<128, 256, 0, stream>>>(hlast, Wout, bout, out);
}

// Round 7
// 1511.648 us; speedup vs baseline: 12.7933x; 12.7933x over previous
//
#include <hip/hip_runtime.h>

// ============================================================================
// 2-layer tanh RNN (B=128,S=512,IN=128,H=512) + linear head (C=1000) + logsoftmax
//
// Round-17: REVERT R16 (cross-WG exchange: 16x regression — a 260ns step
//   cannot afford us-scale cross-CU handoff; per-SIMD 64-MFMA floor is
//   structural). Back to R14/R15 base + one targeted fix: chain-pair
//   interleave for 2x per-wave MFMA ILP.
//   Each MFMA_J was 8 sequentially-dependent MFMAs (accumulator chain): a
//   lone wave issues at 1/latency (~40cy) while its SIMD share is 20.4cy ->
//   pipe half-idle whenever the other wave is in an EPI stretch. Fix:
//   region A = chains 0,1 interleaved (j0k0,j1k0,j0k1,...) + paced ds_reads;
//   region B = chains 2,3 interleaved + EPI0/EPI1 VALU mixed (inputs already
//   complete); tail = EPI2+EPI3 (independent). 2 chains/wave x 2 waves = 4
//   streams -> MFMA pipe can stay full. Per-chain kt order unchanged ->
//   numerics BIT-IDENTICAL. Zero extra registers.
//
// ws layout: bufA = ws (64 MB): xp0/hs0 in place; later Wq1 head + hlast @
//            +1MB. bufB = ws+64MB: Wq0/sc0 head (dead after rec0), later xp1.
// ============================================================================

using short8  = __attribute__((ext_vector_type(8))) short;
using floatx4 = __attribute__((ext_vector_type(4))) float;
using i32x4   = __attribute__((ext_vector_type(4))) int;
using f32x4   = __attribute__((ext_vector_type(4))) float;

#define DEV static __device__ __forceinline__
#define PINA(x) asm volatile("" : "+a"(x))
#define PINV(x) asm volatile("" : "+v"(x))

#define TWO_LOG2E 2.8853900817779268f

#define SGB(m, n) __builtin_amdgcn_sched_group_barrier((m), (n), 0)

DEV void lds_barrier() {
    // LDS-only barrier: do NOT drain vmcnt (global stores/loads keep flying).
    asm volatile("s_waitcnt lgkmcnt(0)\n\ts_barrier" ::: "memory");
}

DEV unsigned short f2bf(float f) {
    union { float f; unsigned u; } v; v.f = f;
    unsigned r = (v.u + 0x7fffu + ((v.u >> 16) & 1u)) >> 16;
    return (unsigned short)r;
}

DEV unsigned short f2h(float f) {
    union { _Float16 h; unsigned short u; } c; c.h = (_Float16)f;
    return c.u;
}

// ---------------------------------------------------------------------------
// packi8: one block (64 thr) per W row j. Row absmax -> per-row scale;
// quantize to i8 in A-frag layout for mfma_i32_16x16x64_i8.
// sc2[j] = mx_j / 127^2 * 2*log2(e)  (dequant folded into exp2 argument).
// ---------------------------------------------------------------------------
__global__ __launch_bounds__(64) void packi8_kernel(
    const float* __restrict__ W, signed char* __restrict__ Wq,
    float* __restrict__ sc2)
{
    const int j = blockIdx.x;            // 0..511
    const int t = threadIdx.x;           // 0..63
    const float* row = W + (size_t)j * 512;

    float4 a = *(const float4*)(row + t * 8);
    float4 b = *(const float4*)(row + t * 8 + 4);
    float m = fmaxf(fmaxf(fabsf(a.x), fabsf(a.y)), fmaxf(fabsf(a.z), fabsf(a.w)));
    m = fmaxf(m, fmaxf(fmaxf(fabsf(b.x), fabsf(b.y)), fabsf(fabsf(b.w) > fabsf(b.z) ? b.w : b.z)));
    #pragma unroll
    for (int off = 32; off; off >>= 1) m = fmaxf(m, __shfl_down(m, off, 64));
    m = __shfl(m, 0, 64);
    if (t == 0) sc2[j] = m * (1.0f / (127.f * 127.f)) * TWO_LOG2E;

    if (t < 32) {
        const int kt = t >> 2, lq = t & 3;
        const int jtg = j >> 4, lm = j & 15;
        const float r = 127.f / m;
        int w4[4];
        #pragma unroll
        for (int w = 0; w < 4; ++w) {
            int v = 0;
            #pragma unroll
            for (int e = 0; e < 4; ++e) {
                int q = __float2int_rn(row[kt * 64 + lq * 16 + w * 4 + e] * r);
                v |= (q & 255) << (8 * e);
            }
            w4[w] = v;
        }
        i32x4 pk; pk[0] = w4[0]; pk[1] = w4[1]; pk[2] = w4[2]; pk[3] = w4[3];
        *(i32x4*)(Wq + ((size_t)((jtg * 8 + kt) * 64 + lq * 16 + lm)) * 16) = pk;
    }
}

// ---------------------------------------------------------------------------
// proj: out[m=t*128+b][n] = f16( (A[m][:]·W[n][:] + b1[n]+b2[n]) * oscale )
// oscale = 2*log2(e): rec consumes xp only inside exp2 arguments (via
// v_fma_mix_f32, so xp lives as packed f16).
// ---------------------------------------------------------------------------
template <int K, int MODE>
__global__ __launch_bounds__(256, 2) void proj_kernel(
    const void* __restrict__ Aptr, const float* __restrict__ W,
    const float* __restrict__ b1, const float* __restrict__ b2,
    unsigned short* __restrict__ out, float oscale)
{
    constexpr int LDA = 40;
    __shared__ unsigned short As[128 * LDA];
    __shared__ unsigned short Ws[64 * LDA];

    const int tid  = threadIdx.x;
    const int lane = tid & 63, wave = tid >> 6;
    const int lm   = lane & 15, lq = lane >> 4;
    const int nbase = blockIdx.x * 64;
    const int mtile = blockIdx.y;
    const int mbase = mtile * 128;

    floatx4 acc[2][4] = {};

    const int ar = tid >> 1, ak = (tid & 1) * 16;
    const int wr = tid >> 2, wk = (tid & 3) * 8;

    for (int k0 = 0; k0 < K; k0 += 32) {
        if (MODE == 0) {
            const float* x   = (const float*)Aptr;
            const float* src = x + ((size_t)ar * 512 + mtile) * 128 + (k0 + ak);
            float4 f0 = *(const float4*)(src + 0);
            float4 f1 = *(const float4*)(src + 4);
            float4 f2 = *(const float4*)(src + 8);
            float4 f3 = *(const float4*)(src + 12);
            unsigned short* d = As + ar * LDA + ak;
            d[0]=f2bf(f0.x); d[1]=f2bf(f0.y); d[2]=f2bf(f0.z); d[3]=f2bf(f0.w);
            d[4]=f2bf(f1.x); d[5]=f2bf(f1.y); d[6]=f2bf(f1.z); d[7]=f2bf(f1.w);
            d[8]=f2bf(f2.x); d[9]=f2bf(f2.y); d[10]=f2bf(f2.z); d[11]=f2bf(f2.w);
            d[12]=f2bf(f3.x); d[13]=f2bf(f3.y); d[14]=f2bf(f3.z); d[15]=f2bf(f3.w);
        } else {
            const unsigned short* h =
                (const unsigned short*)Aptr + (size_t)(mbase + ar) * K + k0 + ak;
            short8 v0 = *(const short8*)(h);
            short8 v1 = *(const short8*)(h + 8);
            *(short8*)(As + ar * LDA + ak)     = v0;
            *(short8*)(As + ar * LDA + ak + 8) = v1;
        }
        {
            const float* src = W + (size_t)(nbase + wr) * K + k0 + wk;
            float4 f0 = *(const float4*)(src);
            float4 f1 = *(const float4*)(src + 4);
            unsigned short* d = Ws + wr * LDA + wk;
            d[0]=f2bf(f0.x); d[1]=f2bf(f0.y); d[2]=f2bf(f0.z); d[3]=f2bf(f0.w);
            d[4]=f2bf(f1.x); d[5]=f2bf(f1.y); d[6]=f2bf(f1.z); d[7]=f2bf(f1.w);
        }
        __syncthreads();

        short8 af0 = *(const short8*)(As + (wave * 32 +  0 + lm) * LDA + lq * 8);
        short8 af1 = *(const short8*)(As + (wave * 32 + 16 + lm) * LDA + lq * 8);
        #pragma unroll
        for (int nt = 0; nt < 4; ++nt) {
            short8 bf = *(const short8*)(Ws + (nt * 16 + lm) * LDA + lq * 8);
            acc[0][nt] = __builtin_amdgcn_mfma_f32_16x16x32_bf16(af0, bf, acc[0][nt], 0, 0, 0);
            acc[1][nt] = __builtin_amdgcn_mfma_f32_16x16x32_bf16(af1, bf, acc[1][nt], 0, 0, 0);
        }
        __syncthreads();
    }

    #pragma unroll
    for (int nt = 0; nt < 4; ++nt) {
        const int n = nbase + nt * 16 + lm;
        const float bias = b1[n] + b2[n];
        #pragma unroll
        for (int mt = 0; mt < 2; ++mt) {
            const int mrow = mbase + wave * 32 + mt * 16 + lq * 4;
            #pragma unroll
            for (int r = 0; r < 4; ++r)
                out[(size_t)(mrow + r) * 512 + n] = f2h((acc[mt][nt][r] + bias) * oscale);
        }
    }
}

// ---------------------------------------------------------------------------
// rec17: 64 WGs x 512 thr (8 waves, 2/SIMD). WG bg owns real batches
// {2bg, 2bg+1} (bb = bg*2 + (lm&1)); lanes lm>=2 replicate; stores lm<2.
// Wave owns 4 j-tiles; W_hh(i8) slice in 128 AGPRs per wave.
// h state: i8 LDS [2][16 b][512 j], 16B-granule swizzle g' = g ^ lm.
// Chain-pair interleave: region A = chains 0,1 (MFMAs alternating) + paced
// ds_reads; region B = chains 2,3 + EPI0/EPI1 VALU mixed; tail EPI2+EPI3.
// MODE 0: store h_t bf16 to hs_out (in-place over xp). MODE 1: t=511 -> h_last.
// ---------------------------------------------------------------------------

#define RD8(P, KT)                                                             \
  (*(const i32x4*)(&h2[P][0] + lm * 512 + ((((KT) * 4 + lq)) ^ lm) * 16))

#define MF(J, KT, CIN)                                                         \
  acc[J] = __builtin_amdgcn_mfma_i32_16x16x64_i8(wa[J][KT], bfr[KT], CIN, 0, 0, 0)

// branchless part of the epilogue (stays in the same scheduling region)
#define EPI_MAIN(JJ, XVROW, HWBUF, QV)                                         \
  {                                                                            \
    const int jtg = wave * 4 + (JJ);                                           \
    float a0 = (float)acc[JJ][0], a1 = (float)acc[JJ][1];                      \
    float a2 = (float)acc[JJ][2], a3 = (float)acc[JJ][3];                      \
    float z0, z1, z2, z3;                                                      \
    asm("v_fma_mix_f32 %0, %1, %2, %3 op_sel:[0,0,0] op_sel_hi:[0,0,1]"        \
        : "=v"(z0) : "v"(a0), "v"(sc[JJ][0]), "v"(XVROW[JJ].x));               \
    asm("v_fma_mix_f32 %0, %1, %2, %3 op_sel:[0,0,1] op_sel_hi:[0,0,1]"        \
        : "=v"(z1) : "v"(a1), "v"(sc[JJ][1]), "v"(XVROW[JJ].x));               \
    asm("v_fma_mix_f32 %0, %1, %2, %3 op_sel:[0,0,0] op_sel_hi:[0,0,1]"        \
        : "=v"(z2) : "v"(a2), "v"(sc[JJ][2]), "v"(XVROW[JJ].y));               \
    asm("v_fma_mix_f32 %0, %1, %2, %3 op_sel:[0,0,1] op_sel_hi:[0,0,1]"        \
        : "=v"(z3) : "v"(a3), "v"(sc[JJ][3]), "v"(XVROW[JJ].y));               \
    float e0 = __builtin_amdgcn_exp2f(z0);                                     \
    float e1 = __builtin_amdgcn_exp2f(z1);                                     \
    float e2 = __builtin_amdgcn_exp2f(z2);                                     \
    float e3 = __builtin_amdgcn_exp2f(z3);                                     \
    float q0 = fmaf(-2.f, __builtin_amdgcn_rcpf(e0 + 1.f), 1.f);               \
    float q1 = fmaf(-2.f, __builtin_amdgcn_rcpf(e1 + 1.f), 1.f);               \
    float q2 = fmaf(-2.f, __builtin_amdgcn_rcpf(e2 + 1.f), 1.f);               \
    float q3 = fmaf(-2.f, __builtin_amdgcn_rcpf(e3 + 1.f), 1.f);               \
    QV.x = q0; QV.y = q1; QV.z = q2; QV.w = q3;                                \
    unsigned m0 = __float_as_uint(fmaf(q0, 127.f, 12582912.f));                \
    unsigned m1 = __float_as_uint(fmaf(q1, 127.f, 12582912.f));                \
    unsigned m2 = __float_as_uint(fmaf(q2, 127.f, 12582912.f));                \
    unsigned m3 = __float_as_uint(fmaf(q3, 127.f, 12582912.f));                \
    unsigned lo = __builtin_amdgcn_perm(m1, m0, 0x00000400u);                  \
    unsigned hi = __builtin_amdgcn_perm(m3, m2, 0x00000400u);                  \
    unsigned qb = __builtin_amdgcn_perm(hi, lo, 0x05040100u);                  \
    *(unsigned*)((HWBUF) + lm * 512 + ((jtg ^ lm) << 4) + lq * 4) = qb;        \
  }

// divergent global-store part (opens a new basic block; kept out of SGB regions)
#define EPI_ST(JJ, QV, TCUR)                                                   \
  {                                                                            \
    if (MODE == 0) {                                                           \
      if (lm < 2) {                                                            \
        uint2 st;                                                              \
        st.x = __builtin_amdgcn_perm(__float_as_uint(QV.y), __float_as_uint(QV.x), 0x07060302u); \
        st.y = __builtin_amdgcn_perm(__float_as_uint(QV.w), __float_as_uint(QV.z), 0x07060302u); \
        *(uint2*)(hst + (JJ) * 16) = st;                                       \
      }                                                                        \
    } else if ((TCUR) == 511) {                                                \
      if (lm < 2) {                                                            \
        const int jtg = wave * 4 + (JJ);                                       \
        *(float4*)(h_last + (size_t)bb * 512 + jtg * 16 + lq * 4) = QV;        \
      }                                                                        \
    }                                                                          \
  }

#define REC_STEP(P, TCUR)                                                      \
  {                                                                            \
    i32x4 bfr[8];                                                              \
    float4 qv0, qv1, qv2, qv3;                                                 \
    _Pragma("unroll")                                                          \
    for (int j = 0; j < 4; ++j)                                                \
      xv[(P) ^ 1][j] = *(const uint2*)(xpt + j * 16);                          \
    xpt += ((TCUR) < 510) ? 65536 : 0;                                         \
    /* region A: 8 ds_reads paced into chains 0,1 interleaved (16 MFMAs) */    \
    bfr[0] = RD8(P, 0);                                                        \
    bfr[1] = RD8(P, 1);                                                        \
    bfr[2] = RD8(P, 2);                                                        \
    bfr[3] = RD8(P, 3);                                                        \
    bfr[4] = RD8(P, 4);                                                        \
    bfr[5] = RD8(P, 5);                                                        \
    bfr[6] = RD8(P, 6);                                                        \
    bfr[7] = RD8(P, 7);                                                        \
    MF(0, 0, z4);     MF(1, 0, z4);                                            \
    MF(0, 1, acc[0]); MF(1, 1, acc[1]);                                        \
    MF(0, 2, acc[0]); MF(1, 2, acc[1]);                                        \
    MF(0, 3, acc[0]); MF(1, 3, acc[1]);                                        \
    MF(0, 4, acc[0]); MF(1, 4, acc[1]);                                        \
    MF(0, 5, acc[0]); MF(1, 5, acc[1]);                                        \
    MF(0, 6, acc[0]); MF(1, 6, acc[1]);                                        \
    MF(0, 7, acc[0]); MF(1, 7, acc[1]);                                        \
    SGB(0x20, 4);   /* xv loads issue first */                                 \
    SGB(0x100, 2);  /* 2 ds_reads ahead */                                     \
    SGB(0x8, 2); SGB(0x100, 1);                                                \
    SGB(0x8, 2); SGB(0x100, 1);                                                \
    SGB(0x8, 2); SGB(0x100, 1);                                                \
    SGB(0x8, 2); SGB(0x100, 1);                                                \
    SGB(0x8, 2); SGB(0x100, 1);                                                \
    SGB(0x8, 2); SGB(0x100, 1);                                                \
    SGB(0x8, 4);                                                               \
    /* region B: chains 2,3 interleaved (16 MFMAs) + EPI0/EPI1 VALU mixed */   \
    MF(2, 0, z4);     MF(3, 0, z4);                                            \
    MF(2, 1, acc[2]); MF(3, 1, acc[3]);                                        \
    MF(2, 2, acc[2]); MF(3, 2, acc[3]);                                        \
    MF(2, 3, acc[2]); MF(3, 3, acc[3]);                                        \
    MF(2, 4, acc[2]); MF(3, 4, acc[3]);                                        \
    MF(2, 5, acc[2]); MF(3, 5, acc[3]);                                        \
    MF(2, 6, acc[2]); MF(3, 6, acc[3]);                                        \
    MF(2, 7, acc[2]); MF(3, 7, acc[3]);                                        \
    EPI_MAIN(0, xv[P], &h2[(P) ^ 1][0], qv0);                                  \
    EPI_MAIN(1, xv[P], &h2[(P) ^ 1][0], qv1);                                  \
    SGB(0x8, 2); SGB(0x2, 8);                                                  \
    SGB(0x8, 2); SGB(0x2, 8);                                                  \
    SGB(0x8, 2); SGB(0x2, 8);                                                  \
    SGB(0x8, 2); SGB(0x2, 8);                                                  \
    SGB(0x8, 2); SGB(0x2, 8);                                                  \
    SGB(0x8, 2); SGB(0x2, 8);                                                  \
    SGB(0x8, 2); SGB(0x2, 8);                                                  \
    SGB(0x8, 2); SGB(0x2, 8);                                                  \
    EPI_ST(0, qv0, TCUR);                                                      \
    EPI_ST(1, qv1, TCUR);                                                      \
    /* tail: EPI2 + EPI3 (independent of each other) */                        \
    EPI_MAIN(2, xv[P], &h2[(P) ^ 1][0], qv2);                                  \
    EPI_MAIN(3, xv[P], &h2[(P) ^ 1][0], qv3);                                  \
    EPI_ST(2, qv2, TCUR);                                                      \
    EPI_ST(3, qv3, TCUR);                                                      \
    if (MODE == 0) hst += 65536;                                               \
    lds_barrier();                                                             \
  }

template <int MODE>
__global__ __launch_bounds__(512, 2) void rec17_kernel(
    const signed char* __restrict__ Wq,   // [32 jtg][8 kt][64 lane][16] i8
    const float* __restrict__ sc2,        // [512] row scale * 2log2e / 127^2
    const unsigned short* xp,             // [S][B][H] f16 SCALED (aliases hs_out)
    unsigned short* hs_out,               // [S][B][H] bf16
    float* __restrict__ h_last)           // [B][H] fp32
{
    __shared__ unsigned char h2[2][16 * 512];   // 16 KB

    const int tid  = threadIdx.x;
    const int lane = tid & 63;
    const int wave = tid >> 6;              // 0..7
    const int lm   = lane & 15, lq = lane >> 4;
    const int bg   = blockIdx.x;            // 0..63
    const int bb   = bg * 2 + (lm & 1);     // 2 real batches replicated over 16 rows

    // ---- W slice in AGPRs: 4 jtg x 8 kt x int4 = 128 AGPRs per wave ----
    i32x4 wa[4][8];
    #pragma unroll
    for (int j = 0; j < 4; ++j) {
        const int jtg = wave * 4 + j;
        #pragma unroll
        for (int kt = 0; kt < 8; ++kt)
            wa[j][kt] = *(const i32x4*)(Wq + ((size_t)((jtg * 8 + kt) * 64 + lane)) * 16);
    }
    #pragma unroll
    for (int j = 0; j < 4; ++j)
        #pragma unroll
        for (int kt = 0; kt < 8; ++kt)
            PINA(wa[j][kt]);

    // ---- per-lane fused dequant scales, pinned ----
    f32x4 sc[4];
    #pragma unroll
    for (int j = 0; j < 4; ++j)
        sc[j] = *(const f32x4*)(sc2 + (wave * 4 + j) * 16 + lq * 4);
    #pragma unroll
    for (int j = 0; j < 4; ++j) PINV(sc[j]);

    // ---- zero h buffers ----
    for (int i = tid; i < 4096; i += 512) ((int*)h2)[i] = 0;
    __syncthreads();

    // per-thread streaming pointers (row stride 128*512 elems per step)
    const unsigned short* xpt = xp + (size_t)bb * 512 + wave * 64 + lq * 4;
    unsigned short*       hst = hs_out + (size_t)bb * 512 + wave * 64 + lq * 4;

    uint2 xv[2][4];
    i32x4 acc[4];
    const i32x4 z4 = {0, 0, 0, 0};

    // ---- prologue: xv[0] = row 0 ----
    #pragma unroll
    for (int j = 0; j < 4; ++j) xv[0][j] = *(const uint2*)(xpt + j * 16);
    xpt += 65536;

    for (int t = 0; t < 512; t += 2) {
        REC_STEP(0, t);
        REC_STEP(1, t + 1);
    }
}

// ---------------------------------------------------------------------------
// head: logits[b][c] = h_last[b][:]·W_out[c][:] + b_out[c]; log_softmax rows.
// ---------------------------------------------------------------------------
__global__ __launch_bounds__(256, 2) void head_kernel(
    const float* __restrict__ hl, const float* __restrict__ Wout,
    const float* __restrict__ bout, float* __restrict__ out)
{
    __shared__ float hrow[512];
    __shared__ float lg[1000];
    __shared__ float red[8];
    const int b = blockIdx.x, tid = threadIdx.x;

    hrow[tid]       = hl[(size_t)b * 512 + tid];
    hrow[tid + 256] = hl[(size_t)b * 512 + 256 + tid];
    __syncthreads();

    float lmax = -1e30f;
    for (int c = tid; c < 1000; c += 256) {
        const float4* w4 = (const float4*)(Wout + (size_t)c * 512);
        float a0 = 0.f, a1 = 0.f, a2 = 0.f, a3 = 0.f;
        #pragma unroll 4
        for (int k = 0; k < 128; ++k) {
            float4 w = w4[k];
            a0 += hrow[4 * k + 0] * w.x;
            a1 += hrow[4 * k + 1] * w.y;
            a2 += hrow[4 * k + 2] * w.z;
            a3 += hrow[4 * k + 3] * w.w;
        }
        float acc = bout[c] + (a0 + a1) + (a2 + a3);
        lg[c] = acc;
        lmax = fmaxf(lmax, acc);
    }
    #pragma unroll
    for (int off = 32; off; off >>= 1) lmax = fmaxf(lmax, __shfl_down(lmax, off, 64));
    if ((tid & 63) == 0) red[tid >> 6] = lmax;
    __syncthreads();
    if (tid == 0) red[4] = fmaxf(fmaxf(red[0], red[1]), fmaxf(red[2], red[3]));
    __syncthreads();
    const float M = red[4];

    float lsum = 0.f;
    for (int c = tid; c < 1000; c += 256) lsum += __expf(lg[c] - M);
    #pragma unroll
    for (int off = 32; off; off >>= 1) lsum += __shfl_down(lsum, off, 64);
    __syncthreads();
    if ((tid & 63) == 0) red[tid >> 6] = lsum;
    __syncthreads();
    if (tid == 0) red[5] = M + __logf(red[0] + red[1] + red[2] + red[3]);
    __syncthreads();
    const float lse = red[5];

    for (int c = tid; c < 1000; c += 256)
        out[(size_t)b * 1000 + c] = lg[c] - lse;
}

// ---------------------------------------------------------------------------
extern "C" void kernel_launch(void* const* d_in, const int* in_sizes, int n_in,
                              void* d_out, int out_size, void* d_ws, size_t ws_size,
                              hipStream_t stream)
{
    const float* x    = (const float*)d_in[0];
    const float* Wih0 = (const float*)d_in[1];
    const float* Whh0 = (const float*)d_in[2];
    const float* bih0 = (const float*)d_in[3];
    const float* bhh0 = (const float*)d_in[4];
    const float* Wih1 = (const float*)d_in[5];
    const float* Whh1 = (const float*)d_in[6];
    const float* bih1 = (const float*)d_in[7];
    const float* bhh1 = (const float*)d_in[8];
    const float* Wout = (const float*)d_in[9];
    const float* bout = (const float*)d_in[10];
    float* out = (float*)d_out;

    char* ws = (char*)d_ws;
    unsigned short* bufA = (unsigned short*)ws;                              // 64 MB
    unsigned short* bufB = (unsigned short*)(ws + (size_t)64 * 1024 * 1024);
    signed char* Wq0 = (signed char*)bufB;                                   // 256 KB (dead after rec0)
    float*       sc0 = (float*)((char*)bufB + 262144);                       // 2 KB
    signed char* Wq1 = (signed char*)bufA;                                   // 256 KB (after proj1 consumed bufA)
    float*       sc1 = (float*)(ws + 262144);                                // 2 KB
    float*     hlast = (float*)(ws + (size_t)1 * 1024 * 1024);               // 256 KB

    const dim3 pgrid(8, 512);

    packi8_kernel<<<512, 64, 0, stream>>>(Whh0, Wq0, sc0);
    proj_kernel<128, 0><<<pgrid, 256, 0, stream>>>((const void*)x, Wih0, bih0, bhh0, bufA, TWO_LOG2E);
    rec17_kernel<0><<<64, 512, 0, stream>>>(Wq0, sc0, bufA, bufA, hlast);

    proj_kernel<512, 1><<<pgrid, 256, 0, stream>>>((const void*)bufA, Wih1, bih1, bhh1, bufB, TWO_LOG2E);
    packi8_kernel<<<512, 64, 0, stream>>>(Whh1, Wq1, sc1);
    rec17_kernel<1><<<64, 512, 0, stream>>>(Wq1, sc1, bufB, bufB, hlast);

    head_kernel<<<128, 256, 0, stream>>>(hlast, Wout, bout, out);
}

// Round 8
// 1429.307 us; speedup vs baseline: 13.5303x; 1.0576x over previous
//
#include <hip/hip_runtime.h>

// ============================================================================
// 2-layer tanh RNN (B=128,S=512,IN=128,H=512) + linear head (C=1000) + logsoftmax
//
// Round-18: rec = EXACT R14 revert (proven best 617 us; R15 rotation null,
//   R16 cross-WG exchange 16x fatal, R17 chain-pairing -4%). rec is at its
//   structural optimum for this decomposition: step 2892 cy vs 1306 cy
//   per-SIMD MFMA floor; residual is barrier-synchronized serial overhead
//   (write -> lgkm -> barrier -> ds_read latency) that intra-step reordering
//   cannot remove, and every structural alternative (stream pairing, 32x32
//   MFMA, H-split) fails the arithmetic.
//   NEW: proj_kernel double-buffered (G15). Old: 2 barriers + exposed
//   global-load latency per k-iter (16 iters for K=512). New: 2 LDS buffer
//   sets (30 KB), register-staged prefetch of tile k+1 issued before tile
//   k's MFMA region, ds_write to idle buffer, ONE barrier per iter.
//   Per-output math order unchanged -> bit-identical numerics.
//
// ws layout: bufA = ws (64 MB): xp0/hs0 in place; later Wq1 head + hlast @
//            +1MB. bufB = ws+64MB: Wq0/sc0 head (dead after rec0), later xp1.
// ============================================================================

using short8  = __attribute__((ext_vector_type(8))) short;
using floatx4 = __attribute__((ext_vector_type(4))) float;
using i32x4   = __attribute__((ext_vector_type(4))) int;
using f32x4   = __attribute__((ext_vector_type(4))) float;

#define DEV static __device__ __forceinline__
#define PINA(x) asm volatile("" : "+a"(x))
#define PINV(x) asm volatile("" : "+v"(x))

#define TWO_LOG2E 2.8853900817779268f

#define SGB(m, n) __builtin_amdgcn_sched_group_barrier((m), (n), 0)

DEV void lds_barrier() {
    // LDS-only barrier: do NOT drain vmcnt (global stores/loads keep flying).
    asm volatile("s_waitcnt lgkmcnt(0)\n\ts_barrier" ::: "memory");
}

DEV unsigned short f2bf(float f) {
    union { float f; unsigned u; } v; v.f = f;
    unsigned r = (v.u + 0x7fffu + ((v.u >> 16) & 1u)) >> 16;
    return (unsigned short)r;
}

DEV unsigned short f2h(float f) {
    union { _Float16 h; unsigned short u; } c; c.h = (_Float16)f;
    return c.u;
}

// ---------------------------------------------------------------------------
// packi8: one block (64 thr) per W row j. Row absmax -> per-row scale;
// quantize to i8 in A-frag layout for mfma_i32_16x16x64_i8.
// sc2[j] = mx_j / 127^2 * 2*log2(e)  (dequant folded into exp2 argument).
// ---------------------------------------------------------------------------
__global__ __launch_bounds__(64) void packi8_kernel(
    const float* __restrict__ W, signed char* __restrict__ Wq,
    float* __restrict__ sc2)
{
    const int j = blockIdx.x;            // 0..511
    const int t = threadIdx.x;           // 0..63
    const float* row = W + (size_t)j * 512;

    float4 a = *(const float4*)(row + t * 8);
    float4 b = *(const float4*)(row + t * 8 + 4);
    float m = fmaxf(fmaxf(fabsf(a.x), fabsf(a.y)), fmaxf(fabsf(a.z), fabsf(a.w)));
    m = fmaxf(m, fmaxf(fmaxf(fabsf(b.x), fabsf(b.y)), fmaxf(fabsf(b.z), fabsf(b.w))));
    #pragma unroll
    for (int off = 32; off; off >>= 1) m = fmaxf(m, __shfl_down(m, off, 64));
    m = __shfl(m, 0, 64);
    if (t == 0) sc2[j] = m * (1.0f / (127.f * 127.f)) * TWO_LOG2E;

    if (t < 32) {
        const int kt = t >> 2, lq = t & 3;
        const int jtg = j >> 4, lm = j & 15;
        const float r = 127.f / m;
        int w4[4];
        #pragma unroll
        for (int w = 0; w < 4; ++w) {
            int v = 0;
            #pragma unroll
            for (int e = 0; e < 4; ++e) {
                int q = __float2int_rn(row[kt * 64 + lq * 16 + w * 4 + e] * r);
                v |= (q & 255) << (8 * e);
            }
            w4[w] = v;
        }
        i32x4 pk; pk[0] = w4[0]; pk[1] = w4[1]; pk[2] = w4[2]; pk[3] = w4[3];
        *(i32x4*)(Wq + ((size_t)((jtg * 8 + kt) * 64 + lq * 16 + lm)) * 16) = pk;
    }
}

// ---------------------------------------------------------------------------
// proj: out[m=t*128+b][n] = f16( (A[m][:]·W[n][:] + b1[n]+b2[n]) * oscale )
// oscale = 2*log2(e): rec consumes xp only inside exp2 arguments (via
// v_fma_mix_f32, so xp lives as packed f16).
// Double-buffered k-loop: prefetch tile k+1 to regs before MFMA(k), write to
// the idle LDS buffer, single barrier per iteration.
// ---------------------------------------------------------------------------
template <int K, int MODE>
__global__ __launch_bounds__(256, 2) void proj_kernel(
    const void* __restrict__ Aptr, const float* __restrict__ W,
    const float* __restrict__ b1, const float* __restrict__ b2,
    unsigned short* __restrict__ out, float oscale)
{
    constexpr int LDA = 40;
    constexpr int NI  = K / 32;
    __shared__ unsigned short As[2][128 * LDA];
    __shared__ unsigned short Ws[2][64 * LDA];

    const int tid  = threadIdx.x;
    const int lane = tid & 63, wave = tid >> 6;
    const int lm   = lane & 15, lq = lane >> 4;
    const int nbase = blockIdx.x * 64;
    const int mtile = blockIdx.y;
    const int mbase = mtile * 128;

    floatx4 acc[2][4] = {};

    const int ar = tid >> 1, ak = (tid & 1) * 16;
    const int wr = tid >> 2, wk = (tid & 3) * 8;

    // staging registers
    float4 xa0, xa1, xa2, xa3;   // MODE 0 A-tile
    short8 ha0, ha1;             // MODE 1 A-tile
    float4 wf0, wf1;             // W tile

    // ---- LOAD(k0): global -> regs ----
#define PROJ_LOAD(k0)                                                          \
    {                                                                          \
        if (MODE == 0) {                                                       \
            const float* x   = (const float*)Aptr;                             \
            const float* src = x + ((size_t)ar * 512 + mtile) * 128 + ((k0) + ak); \
            xa0 = *(const float4*)(src + 0);                                   \
            xa1 = *(const float4*)(src + 4);                                   \
            xa2 = *(const float4*)(src + 8);                                   \
            xa3 = *(const float4*)(src + 12);                                  \
        } else {                                                               \
            const unsigned short* h =                                          \
                (const unsigned short*)Aptr + (size_t)(mbase + ar) * K + (k0) + ak; \
            ha0 = *(const short8*)(h);                                         \
            ha1 = *(const short8*)(h + 8);                                     \
        }                                                                      \
        {                                                                      \
            const float* src = W + (size_t)(nbase + wr) * K + (k0) + wk;       \
            wf0 = *(const float4*)(src);                                       \
            wf1 = *(const float4*)(src + 4);                                   \
        }                                                                      \
    }

    // ---- STORE(buf): regs -> LDS[buf] ----
#define PROJ_STORE(buf)                                                        \
    {                                                                          \
        if (MODE == 0) {                                                       \
            unsigned short* d = &As[buf][0] + ar * LDA + ak;                   \
            d[0]=f2bf(xa0.x); d[1]=f2bf(xa0.y); d[2]=f2bf(xa0.z); d[3]=f2bf(xa0.w); \
            d[4]=f2bf(xa1.x); d[5]=f2bf(xa1.y); d[6]=f2bf(xa1.z); d[7]=f2bf(xa1.w); \
            d[8]=f2bf(xa2.x); d[9]=f2bf(xa2.y); d[10]=f2bf(xa2.z); d[11]=f2bf(xa2.w); \
            d[12]=f2bf(xa3.x); d[13]=f2bf(xa3.y); d[14]=f2bf(xa3.z); d[15]=f2bf(xa3.w); \
        } else {                                                               \
            *(short8*)(&As[buf][0] + ar * LDA + ak)     = ha0;                 \
            *(short8*)(&As[buf][0] + ar * LDA + ak + 8) = ha1;                 \
        }                                                                      \
        {                                                                      \
            unsigned short* d = &Ws[buf][0] + wr * LDA + wk;                   \
            d[0]=f2bf(wf0.x); d[1]=f2bf(wf0.y); d[2]=f2bf(wf0.z); d[3]=f2bf(wf0.w); \
            d[4]=f2bf(wf1.x); d[5]=f2bf(wf1.y); d[6]=f2bf(wf1.z); d[7]=f2bf(wf1.w); \
        }                                                                      \
    }

    // prologue: tile 0 -> LDS[0]
    PROJ_LOAD(0);
    PROJ_STORE(0);
    __syncthreads();

    #pragma unroll
    for (int it = 0; it < NI; ++it) {
        const int cur = it & 1;
        // prefetch next tile (overlaps MFMA below)
        if (it + 1 < NI) PROJ_LOAD((it + 1) * 32);

        short8 af0 = *(const short8*)(&As[cur][0] + (wave * 32 +  0 + lm) * LDA + lq * 8);
        short8 af1 = *(const short8*)(&As[cur][0] + (wave * 32 + 16 + lm) * LDA + lq * 8);
        #pragma unroll
        for (int nt = 0; nt < 4; ++nt) {
            short8 bf = *(const short8*)(&Ws[cur][0] + (nt * 16 + lm) * LDA + lq * 8);
            acc[0][nt] = __builtin_amdgcn_mfma_f32_16x16x32_bf16(af0, bf, acc[0][nt], 0, 0, 0);
            acc[1][nt] = __builtin_amdgcn_mfma_f32_16x16x32_bf16(af1, bf, acc[1][nt], 0, 0, 0);
        }

        if (it + 1 < NI) {
            PROJ_STORE(cur ^ 1);
            __syncthreads();
        }
    }

    #pragma unroll
    for (int nt = 0; nt < 4; ++nt) {
        const int n = nbase + nt * 16 + lm;
        const float bias = b1[n] + b2[n];
        #pragma unroll
        for (int mt = 0; mt < 2; ++mt) {
            const int mrow = mbase + wave * 32 + mt * 16 + lq * 4;
            #pragma unroll
            for (int r = 0; r < 4; ++r)
                out[(size_t)(mrow + r) * 512 + n] = f2h((acc[mt][nt][r] + bias) * oscale);
        }
    }
#undef PROJ_LOAD
#undef PROJ_STORE
}

// ---------------------------------------------------------------------------
// rec18 (= R14's rec14, verbatim): 64 WGs x 512 thr (8 waves, 2/SIMD).
// WG bg owns real batches {2bg, 2bg+1} (bb = bg*2 + (lm&1)); lanes lm>=2
// replicate; stores lm<2. Wave owns 4 j-tiles; W_hh(i8) in 128 AGPRs.
// h state: i8 LDS [2][16 b][512 j], 16B-granule swizzle g' = g ^ lm.
// SGB pins reads-into-chain0 and EPI-into-chain interleave.
// MODE 0: store h_t bf16 to hs_out (in-place over xp). MODE 1: t=511 -> h_last.
// ---------------------------------------------------------------------------

#define RD8(P, KT)                                                             \
  (*(const i32x4*)(&h2[P][0] + lm * 512 + ((((KT) * 4 + lq)) ^ lm) * 16))

#define MFMA_ONE(JJ, KT)                                                       \
  acc[JJ] = __builtin_amdgcn_mfma_i32_16x16x64_i8(                             \
      wa[JJ][KT], bfr[KT], (KT) == 0 ? z4 : acc[JJ], 0, 0, 0)

#define MFMA_J(JJ, BFR)                                                        \
  {                                                                            \
    acc[JJ] = __builtin_amdgcn_mfma_i32_16x16x64_i8(wa[JJ][0], BFR[0], z4, 0, 0, 0); \
    _Pragma("unroll")                                                          \
    for (int kt = 1; kt < 8; ++kt)                                             \
      acc[JJ] = __builtin_amdgcn_mfma_i32_16x16x64_i8(wa[JJ][kt], BFR[kt], acc[JJ], 0, 0, 0); \
  }

// branchless part of the epilogue (stays in the same scheduling region)
#define EPI_MAIN(JJ, XVROW, HWBUF, QV)                                         \
  {                                                                            \
    const int jtg = wave * 4 + (JJ);                                           \
    float a0 = (float)acc[JJ][0], a1 = (float)acc[JJ][1];                      \
    float a2 = (float)acc[JJ][2], a3 = (float)acc[JJ][3];                      \
    float z0, z1, z2, z3;                                                      \
    asm("v_fma_mix_f32 %0, %1, %2, %3 op_sel:[0,0,0] op_sel_hi:[0,0,1]"        \
        : "=v"(z0) : "v"(a0), "v"(sc[JJ][0]), "v"(XVROW[JJ].x));               \
    asm("v_fma_mix_f32 %0, %1, %2, %3 op_sel:[0,0,1] op_sel_hi:[0,0,1]"        \
        : "=v"(z1) : "v"(a1), "v"(sc[JJ][1]), "v"(XVROW[JJ].x));               \
    asm("v_fma_mix_f32 %0, %1, %2, %3 op_sel:[0,0,0] op_sel_hi:[0,0,1]"        \
        : "=v"(z2) : "v"(a2), "v"(sc[JJ][2]), "v"(XVROW[JJ].y));               \
    asm("v_fma_mix_f32 %0, %1, %2, %3 op_sel:[0,0,1] op_sel_hi:[0,0,1]"        \
        : "=v"(z3) : "v"(a3), "v"(sc[JJ][3]), "v"(XVROW[JJ].y));               \
    float e0 = __builtin_amdgcn_exp2f(z0);                                     \
    float e1 = __builtin_amdgcn_exp2f(z1);                                     \
    float e2 = __builtin_amdgcn_exp2f(z2);                                     \
    float e3 = __builtin_amdgcn_exp2f(z3);                                     \
    float q0 = fmaf(-2.f, __builtin_amdgcn_rcpf(e0 + 1.f), 1.f);               \
    float q1 = fmaf(-2.f, __builtin_amdgcn_rcpf(e1 + 1.f), 1.f);               \
    float q2 = fmaf(-2.f, __builtin_amdgcn_rcpf(e2 + 1.f), 1.f);               \
    float q3 = fmaf(-2.f, __builtin_amdgcn_rcpf(e3 + 1.f), 1.f);               \
    QV.x = q0; QV.y = q1; QV.z = q2; QV.w = q3;                                \
    unsigned m0 = __float_as_uint(fmaf(q0, 127.f, 12582912.f));                \
    unsigned m1 = __float_as_uint(fmaf(q1, 127.f, 12582912.f));                \
    unsigned m2 = __float_as_uint(fmaf(q2, 127.f, 12582912.f));                \
    unsigned m3 = __float_as_uint(fmaf(q3, 127.f, 12582912.f));                \
    unsigned lo = __builtin_amdgcn_perm(m1, m0, 0x00000400u);                  \
    unsigned hi = __builtin_amdgcn_perm(m3, m2, 0x00000400u);                  \
    unsigned qb = __builtin_amdgcn_perm(hi, lo, 0x05040100u);                  \
    *(unsigned*)((HWBUF) + lm * 512 + ((jtg ^ lm) << 4) + lq * 4) = qb;        \
  }

// divergent global-store part (opens a new basic block; kept out of SGB regions)
#define EPI_ST(JJ, QV, TCUR)                                                   \
  {                                                                            \
    if (MODE == 0) {                                                           \
      if (lm < 2) {                                                            \
        uint2 st;                                                              \
        st.x = __builtin_amdgcn_perm(__float_as_uint(QV.y), __float_as_uint(QV.x), 0x07060302u); \
        st.y = __builtin_amdgcn_perm(__float_as_uint(QV.w), __float_as_uint(QV.z), 0x07060302u); \
        *(uint2*)(hst + (JJ) * 16) = st;                                       \
      }                                                                        \
    } else if ((TCUR) == 511) {                                                \
      if (lm < 2) {                                                            \
        const int jtg = wave * 4 + (JJ);                                       \
        *(float4*)(h_last + (size_t)bb * 512 + jtg * 16 + lq * 4) = QV;        \
      }                                                                        \
    }                                                                          \
  }

#define SGB8_MIX()                                                             \
  {                                                                            \
    _Pragma("unroll")                                                          \
    for (int u = 0; u < 8; ++u) { SGB(0x8, 1); SGB(0x2, 4); }                  \
  }

#define REC_STEP(P, TCUR)                                                      \
  {                                                                            \
    i32x4 bfr[8];                                                              \
    float4 qv0, qv1, qv2, qv3;                                                 \
    _Pragma("unroll")                                                          \
    for (int j = 0; j < 4; ++j)                                                \
      xv[(P) ^ 1][j] = *(const uint2*)(xpt + j * 16);                          \
    xpt += ((TCUR) < 510) ? 65536 : 0;                                         \
    bfr[0] = RD8(P, 0);                                                        \
    bfr[1] = RD8(P, 1);                                                        \
    bfr[2] = RD8(P, 2);                                                        \
    MFMA_ONE(0, 0);                                                            \
    bfr[3] = RD8(P, 3);                                                        \
    MFMA_ONE(0, 1);                                                            \
    bfr[4] = RD8(P, 4);                                                        \
    MFMA_ONE(0, 2);                                                            \
    bfr[5] = RD8(P, 5);                                                        \
    MFMA_ONE(0, 3);                                                            \
    bfr[6] = RD8(P, 6);                                                        \
    MFMA_ONE(0, 4);                                                            \
    bfr[7] = RD8(P, 7);                                                        \
    MFMA_ONE(0, 5);                                                            \
    MFMA_ONE(0, 6);                                                            \
    MFMA_ONE(0, 7);                                                            \
    SGB(0x20, 4);   /* xv loads issue first */                                 \
    SGB(0x100, 3);  /* 3 ds_reads ahead */                                     \
    SGB(0x8, 1); SGB(0x100, 1);                                                \
    SGB(0x8, 1); SGB(0x100, 1);                                                \
    SGB(0x8, 1); SGB(0x100, 1);                                                \
    SGB(0x8, 1); SGB(0x100, 1);                                                \
    SGB(0x8, 1); SGB(0x100, 1);                                                \
    SGB(0x8, 3);                                                               \
    MFMA_J(1, bfr);                                                            \
    EPI_MAIN(0, xv[P], &h2[(P) ^ 1][0], qv0);                                  \
    SGB8_MIX();                                                                \
    EPI_ST(0, qv0, TCUR);                                                      \
    MFMA_J(2, bfr);                                                            \
    EPI_MAIN(1, xv[P], &h2[(P) ^ 1][0], qv1);                                  \
    SGB8_MIX();                                                                \
    EPI_ST(1, qv1, TCUR);                                                      \
    MFMA_J(3, bfr);                                                            \
    EPI_MAIN(2, xv[P], &h2[(P) ^ 1][0], qv2);                                  \
    SGB8_MIX();                                                                \
    EPI_ST(2, qv2, TCUR);                                                      \
    EPI_MAIN(3, xv[P], &h2[(P) ^ 1][0], qv3);                                  \
    EPI_ST(3, qv3, TCUR);                                                      \
    if (MODE == 0) hst += 65536;                                               \
    lds_barrier();                                                             \
  }

template <int MODE>
__global__ __launch_bounds__(512, 2) void rec18_kernel(
    const signed char* __restrict__ Wq,   // [32 jtg][8 kt][64 lane][16] i8
    const float* __restrict__ sc2,        // [512] row scale * 2log2e / 127^2
    const unsigned short* xp,             // [S][B][H] f16 SCALED (aliases hs_out)
    unsigned short* hs_out,               // [S][B][H] bf16
    float* __restrict__ h_last)           // [B][H] fp32
{
    __shared__ unsigned char h2[2][16 * 512];   // 16 KB

    const int tid  = threadIdx.x;
    const int lane = tid & 63;
    const int wave = tid >> 6;              // 0..7
    const int lm   = lane & 15, lq = lane >> 4;
    const int bg   = blockIdx.x;            // 0..63
    const int bb   = bg * 2 + (lm & 1);     // 2 real batches replicated over 16 rows

    // ---- W slice in AGPRs: 4 jtg x 8 kt x int4 = 128 AGPRs per wave ----
    i32x4 wa[4][8];
    #pragma unroll
    for (int j = 0; j < 4; ++j) {
        const int jtg = wave * 4 + j;
        #pragma unroll
        for (int kt = 0; kt < 8; ++kt)
            wa[j][kt] = *(const i32x4*)(Wq + ((size_t)((jtg * 8 + kt) * 64 + lane)) * 16);
    }
    #pragma unroll
    for (int j = 0; j < 4; ++j)
        #pragma unroll
        for (int kt = 0; kt < 8; ++kt)
            PINA(wa[j][kt]);

    // ---- per-lane fused dequant scales, pinned ----
    f32x4 sc[4];
    #pragma unroll
    for (int j = 0; j < 4; ++j)
        sc[j] = *(const f32x4*)(sc2 + (wave * 4 + j) * 16 + lq * 4);
    #pragma unroll
    for (int j = 0; j < 4; ++j) PINV(sc[j]);

    // ---- zero h buffers ----
    for (int i = tid; i < 4096; i += 512) ((int*)h2)[i] = 0;
    __syncthreads();

    // per-thread streaming pointers (row stride 128*512 elems per step)
    const unsigned short* xpt = xp + (size_t)bb * 512 + wave * 64 + lq * 4;
    unsigned short*       hst = hs_out + (size_t)bb * 512 + wave * 64 + lq * 4;

    uint2 xv[2][4];
    i32x4 acc[4];
    const i32x4 z4 = {0, 0, 0, 0};

    // ---- prologue: xv[0] = row 0 ----
    #pragma unroll
    for (int j = 0; j < 4; ++j) xv[0][j] = *(const uint2*)(xpt + j * 16);
    xpt += 65536;

    for (int t = 0; t < 512; t += 2) {
        REC_STEP(0, t);
        REC_STEP(1, t + 1);
    }
}

// ---------------------------------------------------------------------------
// head: logits[b][c] = h_last[b][:]·W_out[c][:] + b_out[c]; log_softmax rows.
// ---------------------------------------------------------------------------
__global__ __launch_bounds__(256, 2) void head_kernel(
    const float* __restrict__ hl, const float* __restrict__ Wout,
    const float* __restrict__ bout, float* __restrict__ out)
{
    __shared__ float hrow[512];
    __shared__ float lg[1000];
    __shared__ float red[8];
    const int b = blockIdx.x, tid = threadIdx.x;

    hrow[tid]       = hl[(size_t)b * 512 + tid];
    hrow[tid + 256] = hl[(size_t)b * 512 + 256 + tid];
    __syncthreads();

    float lmax = -1e30f;
    for (int c = tid; c < 1000; c += 256) {
        const float4* w4 = (const float4*)(Wout + (size_t)c * 512);
        float a0 = 0.f, a1 = 0.f, a2 = 0.f, a3 = 0.f;
        #pragma unroll 4
        for (int k = 0; k < 128; ++k) {
            float4 w = w4[k];
            a0 += hrow[4 * k + 0] * w.x;
            a1 += hrow[4 * k + 1] * w.y;
            a2 += hrow[4 * k + 2] * w.z;
            a3 += hrow[4 * k + 3] * w.w;
        }
        float acc = bout[c] + (a0 + a1) + (a2 + a3);
        lg[c] = acc;
        lmax = fmaxf(lmax, acc);
    }
    #pragma unroll
    for (int off = 32; off; off >>= 1) lmax = fmaxf(lmax, __shfl_down(lmax, off, 64));
    if ((tid & 63) == 0) red[tid >> 6] = lmax;
    __syncthreads();
    if (tid == 0) red[4] = fmaxf(fmaxf(red[0], red[1]), fmaxf(red[2], red[3]));
    __syncthreads();
    const float M = red[4];

    float lsum = 0.f;
    for (int c = tid; c < 1000; c += 256) lsum += __expf(lg[c] - M);
    #pragma unroll
    for (int off = 32; off; off >>= 1) lsum += __shfl_down(lsum, off, 64);
    __syncthreads();
    if ((tid & 63) == 0) red[tid >> 6] = lsum;
    __syncthreads();
    if (tid == 0) red[5] = M + __logf(red[0] + red[1] + red[2] + red[3]);
    __syncthreads();
    const float lse = red[5];

    for (int c = tid; c < 1000; c += 256)
        out[(size_t)b * 1000 + c] = lg[c] - lse;
}

// ---------------------------------------------------------------------------
extern "C" void kernel_launch(void* const* d_in, const int* in_sizes, int n_in,
                              void* d_out, int out_size, void* d_ws, size_t ws_size,
                              hipStream_t stream)
{
    const float* x    = (const float*)d_in[0];
    const float* Wih0 = (const float*)d_in[1];
    const float* Whh0 = (const float*)d_in[2];
    const float* bih0 = (const float*)d_in[3];
    const float* bhh0 = (const float*)d_in[4];
    const float* Wih1 = (const float*)d_in[5];
    const float* Whh1 = (const float*)d_in[6];
    const float* bih1 = (const float*)d_in[7];
    const float* bhh1 = (const float*)d_in[8];
    const float* Wout = (const float*)d_in[9];
    const float* bout = (const float*)d_in[10];
    float* out = (float*)d_out;

    char* ws = (char*)d_ws;
    unsigned short* bufA = (unsigned short*)ws;                              // 64 MB
    unsigned short* bufB = (unsigned short*)(ws + (size_t)64 * 1024 * 1024);
    signed char* Wq0 = (signed char*)bufB;                                   // 256 KB (dead after rec0)
    float*       sc0 = (float*)((char*)bufB + 262144);                       // 2 KB
    signed char* Wq1 = (signed char*)bufA;                                   // 256 KB (after proj1 consumed bufA)
    float*       sc1 = (float*)(ws + 262144);                                // 2 KB
    float*     hlast = (float*)(ws + (size_t)1 * 1024 * 1024);               // 256 KB

    const dim3 pgrid(8, 512);

    packi8_kernel<<<512, 64, 0, stream>>>(Whh0, Wq0, sc0);
    proj_kernel<128, 0><<<pgrid, 256, 0, stream>>>((const void*)x, Wih0, bih0, bhh0, bufA, TWO_LOG2E);
    rec18_kernel<0><<<64, 512, 0, stream>>>(Wq0, sc0, bufA, bufA, hlast);

    proj_kernel<512, 1><<<pgrid, 256, 0, stream>>>((const void*)bufA, Wih1, bih1, bhh1, bufB, TWO_LOG2E);
    packi8_kernel<<<512, 64, 0, stream>>>(Whh1, Wq1, sc1);
    rec18_kernel<1><<<64, 512, 0, stream>>>(Wq1, sc1, bufB, bufB, hlast);

    head_kernel<<<128, 256, 0, stream>>>(hlast, Wout, bout, out);
}